// Round 4
// baseline (812.132 us; speedup 1.0000x reference)
//
#include <hip/hip_runtime.h>
#include <math.h>

#ifndef M_PI
#define M_PI 3.14159265358979323846
#endif

#define BB     128
#define TT     16384
#define PP     20
#define NCH    18
#define CHUNK  64
#define WARM   192
#define NCHUNK (TT / CHUNK)   // 256
#define BUF    8

typedef float f32x4 __attribute__((ext_vector_type(4)));

// bipolar pair probe indices (LL, LP, RP, RL, Z groups, insertion order)
__constant__ int d_P1[NCH] = {0,4,5,6,  0,1,2,3,  11,15,16,17, 11,12,13,14, 8,9};
__constant__ int d_P2[NCH] = {4,5,6,7,  1,2,3,7,  15,16,17,18, 12,13,14,18, 9,10};

struct Coeffs {
    float b0h, b1h, b2h, a1h, a2h;   // highpass (normalized by a0)
    float b0l, b1l, b2l, a1l, a2l;   // lowpass
};

__global__ __launch_bounds__(256) void collate_iir(
    const float* __restrict__ x, const float* __restrict__ msk,
    float* __restrict__ out, Coeffs cf)
{
    int tid   = blockIdx.x * blockDim.x + threadIdx.x;
    int c     = tid % NCH;          // channel 0..17
    int g     = tid / NCH;          // row-chunk group
    int chunk = g & (NCHUNK - 1);   // 0..255
    int b     = g >> 8;             // 0..127   (g / NCHUNK)

    int p1 = d_P1[c];
    int p2 = d_P2[c];

    const float* xb = x   + (size_t)b * TT * PP;
    const float* mb = msk + (size_t)b * TT * PP;
    float* oe = out + ((size_t)b * NCH + c) * TT;                             // eegs
    float* om = out + (size_t)BB * NCH * TT + ((size_t)b * NCH + c) * TT;     // eeg_masks

    int tstart = chunk * CHUNK;
    int w0     = tstart - WARM;
    if (w0 < 0) w0 = 0;

    // direct-form-I state, zero initial conditions
    float hx1 = 0.f, hx2 = 0.f, hy1 = 0.f, hy2 = 0.f;   // highpass
    float lx1 = 0.f, lx2 = 0.f, ly1 = 0.f, ly2 = 0.f;   // lowpass

    float xv1[BUF], xv2[BUF], mv1[BUF], mv2[BUF];
    float pm = 0.f, ly = 0.f;   // latest pair-mask and lowpass output

    // ---- warm-up region: run filters, discard output --------------------
    for (int t0 = w0; t0 < tstart; t0 += BUF) {
#pragma unroll
        for (int k = 0; k < BUF; ++k) {
            int idx = (t0 + k) * PP;
            xv1[k] = xb[idx + p1];
            xv2[k] = xb[idx + p2];
            mv1[k] = mb[idx + p1];
            mv2[k] = mb[idx + p2];
        }
#pragma unroll
        for (int k = 0; k < BUF; ++k) {
            pm = mv1[k] * mv2[k];
            float v  = (xv1[k] - xv2[k]) * pm;
            float hy = cf.b0h * v + cf.b1h * hx1 + cf.b2h * hx2
                     - cf.a1h * hy1 - cf.a2h * hy2;
            hx2 = hx1; hx1 = v;  hy2 = hy1; hy1 = hy;
            ly = cf.b0l * hy + cf.b1l * lx1 + cf.b2l * lx2
               - cf.a1l * ly1 - cf.a2l * ly2;
            lx2 = lx1; lx1 = hy; ly2 = ly1; ly1 = ly;
        }
    }

    // ---- emit region: load block, filter from regs, store float4 --------
    int tend = tstart + CHUNK;
    for (int t0 = tstart; t0 < tend; t0 += BUF) {
#pragma unroll
        for (int k = 0; k < BUF; ++k) {
            int idx = (t0 + k) * PP;
            xv1[k] = xb[idx + p1];
            xv2[k] = xb[idx + p2];
            mv1[k] = mb[idx + p1];
            mv2[k] = mb[idx + p2];
        }
        float be[BUF], bm[BUF];
#pragma unroll
        for (int k = 0; k < BUF; ++k) {
            pm = mv1[k] * mv2[k];
            float v  = (xv1[k] - xv2[k]) * pm;
            float hy = cf.b0h * v + cf.b1h * hx1 + cf.b2h * hx2
                     - cf.a1h * hy1 - cf.a2h * hy2;
            hx2 = hx1; hx1 = v;  hy2 = hy1; hy1 = hy;
            ly = cf.b0l * hy + cf.b1l * lx1 + cf.b2l * lx2
               - cf.a1l * ly1 - cf.a2l * ly2;
            lx2 = lx1; lx1 = hy; ly2 = ly1; ly1 = ly;
            be[k] = ly;
            bm[k] = pm;
        }
        f32x4* oe4 = reinterpret_cast<f32x4*>(oe + t0);
        f32x4* om4 = reinterpret_cast<f32x4*>(om + t0);
#pragma unroll
        for (int q = 0; q < BUF / 4; ++q) {
            f32x4 ve = { be[4*q+0], be[4*q+1], be[4*q+2], be[4*q+3] };
            f32x4 vm = { bm[4*q+0], bm[4*q+1], bm[4*q+2], bm[4*q+3] };
            __builtin_nontemporal_store(ve, oe4 + q);
            __builtin_nontemporal_store(vm, om4 + q);
        }
    }
}

extern "C" void kernel_launch(void* const* d_in, const int* in_sizes, int n_in,
                              void* d_out, int out_size, void* d_ws, size_t ws_size,
                              hipStream_t stream)
{
    const float* x = (const float*)d_in[0];
    const float* m = (const float*)d_in[1];
    float* out = (float*)d_out;

    const double sr = 40.0, q = 0.7071067811865476;
    Coeffs cf;
    {   // highpass fc = 0.5
        double w0 = 2.0 * M_PI * 0.5 / sr;
        double al = sin(w0) / (2.0 * q);
        double cw = cos(w0);
        double a0 = 1.0 + al;
        cf.b0h = (float)(((1.0 + cw) * 0.5) / a0);
        cf.b1h = (float)((-(1.0 + cw)) / a0);
        cf.b2h = cf.b0h;
        cf.a1h = (float)((-2.0 * cw) / a0);
        cf.a2h = (float)((1.0 - al) / a0);
    }
    {   // lowpass fc = 50
        double w0 = 2.0 * M_PI * 50.0 / sr;
        double al = sin(w0) / (2.0 * q);
        double cw = cos(w0);
        double a0 = 1.0 + al;
        cf.b0l = (float)(((1.0 - cw) * 0.5) / a0);
        cf.b1l = (float)((1.0 - cw) / a0);
        cf.b2l = cf.b0l;
        cf.a1l = (float)((-2.0 * cw) / a0);
        cf.a2l = (float)((1.0 - al) / a0);
    }

    int total  = BB * NCHUNK * NCH;   // 589824
    int block  = 256;
    int grid   = total / block;       // 2304
    collate_iir<<<grid, block, 0, stream>>>(x, m, out, cf);
}

// Round 5
// 279.429 us; speedup vs baseline: 2.9064x; 2.9064x over previous
//
#include <hip/hip_runtime.h>
#include <math.h>

#ifndef M_PI
#define M_PI 3.14159265358979323846
#endif

#define BB     128
#define TT     16384
#define PP     20
#define NCH    18
#define EMIT   256                 // emitted samples per block
#define WARM   128                 // warm-up samples (pole 0.946^128 ~ 8e-4)
#define ROWS   (WARM + EMIT)       // 384 rows staged in LDS
#define NCHUNK (TT / EMIT)         // 64
#define WEMIT  (EMIT / 4)          // 64 rows emitted per wave

typedef float f32x4 __attribute__((ext_vector_type(4)));

// bipolar pair probe indices (LL, LP, RP, RL, Z groups, insertion order)
__constant__ int d_P1[NCH] = {0,4,5,6,  0,1,2,3,  11,15,16,17, 11,12,13,14, 8,9};
__constant__ int d_P2[NCH] = {4,5,6,7,  1,2,3,7,  15,16,17,18, 12,13,14,18, 9,10};

struct Coeffs {
    float b0h, b1h, b2h, a1h, a2h;   // highpass (normalized by a0)
    float b0l, b1l, b2l, a1l, a2l;   // lowpass
};

__global__ __launch_bounds__(256) void collate_iir(
    const float* __restrict__ x, const float* __restrict__ msk,
    float* __restrict__ out, Coeffs cf)
{
    __shared__ float sx[ROWS * PP];   // 30 KB
    __shared__ float sm[ROWS * PP];   // 30 KB

    int blk   = blockIdx.x;
    int chunk = blk & (NCHUNK - 1);
    int b     = blk >> 6;             // blk / NCHUNK
    int t0    = chunk * EMIT;
    int base  = t0 - WARM; if (base < 0) base = 0;
    int nwarm = t0 - base;            // 0 (chunk 0) or 128
    int nrows = nwarm + EMIT;
    int nf4   = nrows * PP / 4;       // 1280 or 1920 float4s

    // ---- cooperative streaming load: contiguous slab, fully coalesced ----
    const f32x4* gx = reinterpret_cast<const f32x4*>(x   + ((size_t)b * TT + base) * PP);
    const f32x4* gm = reinterpret_cast<const f32x4*>(msk + ((size_t)b * TT + base) * PP);
    f32x4* lsx = reinterpret_cast<f32x4*>(sx);
    f32x4* lsm = reinterpret_cast<f32x4*>(sm);
    for (int i = threadIdx.x; i < nf4; i += 256) {
        lsx[i] = gx[i];
        lsm[i] = gm[i];
    }
    __syncthreads();

    // ---- per-wave IIR: wave owns a 64-sample quarter, lanes = channels ----
    int wid  = threadIdx.x >> 6;
    int lane = threadIdx.x & 63;
    if (lane >= NCH) return;
    int c  = lane;
    int p1 = d_P1[c], p2 = d_P2[c];

    int erow = nwarm + wid * WEMIT;            // first emitted tile-row
    int wrow = erow - WARM; if (wrow < 0) wrow = 0;

    float hx1 = 0.f, hx2 = 0.f, hy1 = 0.f, hy2 = 0.f;   // highpass state
    float lx1 = 0.f, lx2 = 0.f, ly1 = 0.f, ly2 = 0.f;   // lowpass state

    // warm-up from LDS (discard output)
#pragma unroll 4
    for (int r = wrow; r < erow; ++r) {
        int o = r * PP;
        float pm = sm[o + p1] * sm[o + p2];
        float v  = (sx[o + p1] - sx[o + p2]) * pm;
        float hy = cf.b0h * v + cf.b1h * hx1 + cf.b2h * hx2
                 - cf.a1h * hy1 - cf.a2h * hy2;
        hx2 = hx1; hx1 = v;  hy2 = hy1; hy1 = hy;
        float ly = cf.b0l * hy + cf.b1l * lx1 + cf.b2l * lx2
                 - cf.a1l * ly1 - cf.a2l * ly2;
        lx2 = lx1; lx1 = hy; ly2 = ly1; ly1 = ly;
    }

    // emit region: 64 samples, store as float4 every 4 steps
    size_t rowoff = ((size_t)b * NCH + c) * TT + (size_t)t0 + (size_t)wid * WEMIT;
    float* oe = out + rowoff;                                  // eegs
    float* om = out + (size_t)BB * NCH * TT + rowoff;          // eeg_masks

    for (int gq = 0; gq < WEMIT / 4; ++gq) {
        float be[4], bm[4];
#pragma unroll
        for (int k = 0; k < 4; ++k) {
            int o = (erow + gq * 4 + k) * PP;
            float pm = sm[o + p1] * sm[o + p2];
            float v  = (sx[o + p1] - sx[o + p2]) * pm;
            float hy = cf.b0h * v + cf.b1h * hx1 + cf.b2h * hx2
                     - cf.a1h * hy1 - cf.a2h * hy2;
            hx2 = hx1; hx1 = v;  hy2 = hy1; hy1 = hy;
            float ly = cf.b0l * hy + cf.b1l * lx1 + cf.b2l * lx2
                     - cf.a1l * ly1 - cf.a2l * ly2;
            lx2 = lx1; lx1 = hy; ly2 = ly1; ly1 = ly;
            be[k] = ly;
            bm[k] = pm;
        }
        f32x4 ve = { be[0], be[1], be[2], be[3] };
        f32x4 vm = { bm[0], bm[1], bm[2], bm[3] };
        *reinterpret_cast<f32x4*>(oe + gq * 4) = ve;
        *reinterpret_cast<f32x4*>(om + gq * 4) = vm;
    }
}

extern "C" void kernel_launch(void* const* d_in, const int* in_sizes, int n_in,
                              void* d_out, int out_size, void* d_ws, size_t ws_size,
                              hipStream_t stream)
{
    const float* x = (const float*)d_in[0];
    const float* m = (const float*)d_in[1];
    float* out = (float*)d_out;

    const double sr = 40.0, q = 0.7071067811865476;
    Coeffs cf;
    {   // highpass fc = 0.5
        double w0 = 2.0 * M_PI * 0.5 / sr;
        double al = sin(w0) / (2.0 * q);
        double cw = cos(w0);
        double a0 = 1.0 + al;
        cf.b0h = (float)(((1.0 + cw) * 0.5) / a0);
        cf.b1h = (float)((-(1.0 + cw)) / a0);
        cf.b2h = cf.b0h;
        cf.a1h = (float)((-2.0 * cw) / a0);
        cf.a2h = (float)((1.0 - al) / a0);
    }
    {   // lowpass fc = 50
        double w0 = 2.0 * M_PI * 50.0 / sr;
        double al = sin(w0) / (2.0 * q);
        double cw = cos(w0);
        double a0 = 1.0 + al;
        cf.b0l = (float)(((1.0 - cw) * 0.5) / a0);
        cf.b1l = (float)((1.0 - cw) / a0);
        cf.b2l = cf.b0l;
        cf.a1l = (float)((-2.0 * cw) / a0);
        cf.a2l = (float)((1.0 - al) / a0);
    }

    int grid  = BB * NCHUNK;   // 8192 blocks, one per (batch, 256-sample chunk)
    collate_iir<<<grid, 256, 0, stream>>>(x, m, out, cf);
}